// Round 12
// baseline (111.786 us; speedup 1.0000x reference)
//
#include <hip/hip_runtime.h>
#include <cstdint>
#include <cstddef>

#define FMIN_F (-3.402823466e38f)

__device__ __forceinline__ float wave_sum(float v) {
#pragma unroll
    for (int off = 32; off > 0; off >>= 1)
        v += __shfl_down(v, off, 64);
    return v; // valid in lane 0
}

// ---------------- GEMV: batch-twin, full-TLP ----------------
// R3-R11 matrix: every shape (any pattern/X-path/VGPR state) = 2.4-2.5 TB/s;
// healthy streamers (copy 6.3, RMSNorm 4.9) share ONE property my GEMVs
// lacked: ~32 waves/CU with no LDS cap. This kernel: block = (mat, 16-row
// chunk, ONE batch) -> X LDS = 16KB -> 8 blocks/CU = 32 waves/CU; body needs
// ~56 VGPR (w 32 + acc 4 + x 8 + addr), under the 64 cliff BY DESIGN.
// W read 4x raw, but the 4 batch-twins of a chunk are placed on the SAME XCD
// within 24 dispatch ordinals (ord bits [2:0]=chunk-low, [4:3]=batch,
// [5:]=chunk-high) -> 3/4 reads are L2 hits (chunk=256KB << 4MB L2).
// Full K per wave -> final biased output, no reduce kernels.
template <int NMAT>
__global__ __launch_bounds__(256) void gemv_tw_kernel(
    const float* __restrict__ X,                   // [4][4096]
    const float* __restrict__ W0, const float* __restrict__ B0,
    const float* __restrict__ W1, const float* __restrict__ B1,
    const float* __restrict__ W2, const float* __restrict__ B2,
    float scale0,
    float* __restrict__ Y)                         // [NMAT*4][4096]
{
    const int o     = blockIdx.x;
    const int batch = (o >> 3) & 3;
    const int cm    = (o >> 5) * 8 + (o & 7);      // chunk-mat id
    const int mi    = (NMAT == 1) ? 0 : (cm >> 8);
    const int chunk = cm & 255;

    __shared__ float4 sX[1024];                    // 16 KB: one batch's X
    const int tid = threadIdx.x;
    const float4* X4 = (const float4*)X + (size_t)batch * 1024;
    for (int i = tid; i < 1024; i += 256) sX[i] = X4[i];
    __syncthreads();

    const int wave = tid >> 6;
    const int lane = tid & 63;
    const int r0   = chunk * 16 + wave * 4;        // first of 4 rows

    const float* W  = (mi == 0) ? W0 : (mi == 1) ? W1 : W2;
    const float* Bs = (mi == 0) ? B0 : (mi == 1) ? B1 : B2;
    const float4* Wr0 = (const float4*)W + (size_t)(r0 + 0) * 1024;
    const float4* Wr1 = Wr0 + 1024;
    const float4* Wr2 = Wr0 + 2048;
    const float4* Wr3 = Wr0 + 3072;

    float acc0 = 0.f, acc1 = 0.f, acc2 = 0.f, acc3 = 0.f;

#pragma unroll 1
    for (int s = 0; s < 8; ++s) {
        const int p0 = s * 128 + lane;
        const int p1 = p0 + 64;
        // 8 independent 16B loads (32 VGPR buffer), single-buffered; TLP
        // across 32 waves/CU covers the latency (RMSNorm recipe).
        const float4 wa0 = Wr0[p0], wb0 = Wr0[p1];
        const float4 wa1 = Wr1[p0], wb1 = Wr1[p1];
        const float4 wa2 = Wr2[p0], wb2 = Wr2[p1];
        const float4 wa3 = Wr3[p0], wb3 = Wr3[p1];
        const float4 x0 = sX[p0];
        const float4 x1 = sX[p1];
        acc0 += wa0.x * x0.x + wa0.y * x0.y + wa0.z * x0.z + wa0.w * x0.w
              + wb0.x * x1.x + wb0.y * x1.y + wb0.z * x1.z + wb0.w * x1.w;
        acc1 += wa1.x * x0.x + wa1.y * x0.y + wa1.z * x0.z + wa1.w * x0.w
              + wb1.x * x1.x + wb1.y * x1.y + wb1.z * x1.z + wb1.w * x1.w;
        acc2 += wa2.x * x0.x + wa2.y * x0.y + wa2.z * x0.z + wa2.w * x0.w
              + wb2.x * x1.x + wb2.y * x1.y + wb2.z * x1.z + wb2.w * x1.w;
        acc3 += wa3.x * x0.x + wa3.y * x0.y + wa3.z * x0.z + wa3.w * x0.w
              + wb3.x * x1.x + wb3.y * x1.y + wb3.z * x1.z + wb3.w * x1.w;
    }

    acc0 = wave_sum(acc0);
    acc1 = wave_sum(acc1);
    acc2 = wave_sum(acc2);
    acc3 = wave_sum(acc3);
    if (lane == 0) {
        float* y = Y + ((size_t)(mi * 4 + batch)) * 4096 + r0;
        const float sc = (mi == 0) ? scale0 : 1.0f;
        y[0] = (acc0 + Bs[r0 + 0]) * sc;
        y[1] = (acc1 + Bs[r0 + 1]) * sc;
        y[2] = (acc2 + Bs[r0 + 2]) * sc;
        y[3] = (acc3 + Bs[r0 + 3]) * sc;
    }
}

// ---------------- Attention phase 1: scores ----------------
__global__ __launch_bounds__(256) void score_kernel(
    const float* __restrict__ qkv,     // [3][4][4096]
    const float* __restrict__ pk,      // [B,H,2048,128]
    const float* __restrict__ amask,   // [B,1,1,2049]
    const float* __restrict__ cam,     // [B*H,1,2049]
    const int* __restrict__ sbp, const int* __restrict__ rbp,
    float* __restrict__ scores)        // [128][512]
{
    constexpr int PAST = 2048, S = 2049, HD = 128;
    const int bh = blockIdx.y;
    const int b  = bh >> 5;
    const int h  = bh & 31;
    const int SB = sbp[0], RB = rbp[0];
    const int NS = SB + 1;
    const int NA = NS + RB + 1;

    const int wave = threadIdx.x >> 6;
    const int lane = threadIdx.x & 63;

    const float* qh   = qkv + (size_t)b * 4096 + h * HD;
    const float* knew = qkv + (size_t)(4 + b) * 4096 + h * HD;
    const float2 ql = ((const float2*)qh)[lane];

#pragma unroll
    for (int j = 0; j < 8; ++j) {
        const int i = blockIdx.x * 32 + j * 4 + wave;
        if (i >= NA) continue;
        const int s = (i < NS) ? i : (PAST - RB + (i - NS));
        const float2* kr = (s < PAST)
            ? (const float2*)(pk + ((size_t)bh * PAST + s) * HD)
            : (const float2*)knew;
        const float2 kk = kr[lane];
        float p = ql.x * kk.x + ql.y * kk.y;
        p = wave_sum(p);
        if (lane == 0) {
            const float m  = cam[(size_t)bh * S + s];
            float sc = fmaxf(p + amask[(size_t)b * S + s], FMIN_F);
            sc = sc * m + (1.0f - m) * FMIN_F;
            scores[(size_t)bh * 512 + i] = sc;
        }
    }
}

// ---------------- Attention phase 2: softmax + coefficient fixups ----------------
__global__ __launch_bounds__(256) void softmax_kernel(
    const float* __restrict__ ps,      // [B*H,2048]
    const int* __restrict__ sbp, const int* __restrict__ rbp,
    float* __restrict__ scores)        // [128][512] in/out
{
    constexpr int PAST = 2048;
    const int bh = blockIdx.x;
    const int SB = sbp[0], RB = rbp[0];
    const int NS = SB + 1;
    const int NA = NS + RB + 1;
    const int tid = threadIdx.x;

    __shared__ float s_c[512];
    __shared__ float s_red[256];
    __shared__ float s_mm;

    for (int i = tid; i < NA; i += 256) s_c[i] = scores[(size_t)bh * 512 + i];

    {
        float part = 0.0f;
        const int cnt = SB + RB;
        for (int i = tid; i < cnt; i += 256) {
            const int idx = (i < SB) ? i : (PAST - RB + (i - SB));
            part += ps[(size_t)bh * PAST + idx];
        }
        s_red[tid] = part;
    }
    __syncthreads();
#pragma unroll
    for (int st = 128; st > 0; st >>= 1) {
        if (tid < st) s_red[tid] += s_red[tid + st];
        __syncthreads();
    }
    if (tid == 0) {
        const float mean = s_red[0] / (float)(SB + RB);
        const float prob = ps[(size_t)bh * PAST + (PAST - RB)] / mean;
        s_mm = (prob > 1.0f) ? (1.0f / 32.0f) : 0.0f;
    }
    __syncthreads();

    float mx = -INFINITY;
    for (int i = tid; i < NA; i += 256) mx = fmaxf(mx, s_c[i]);
    s_red[tid] = mx;
    __syncthreads();
#pragma unroll
    for (int st = 128; st > 0; st >>= 1) {
        if (tid < st) s_red[tid] = fmaxf(s_red[tid], s_red[tid + st]);
        __syncthreads();
    }
    const float gmax = s_red[0];
    __syncthreads();

    float lsum = 0.0f;
    for (int i = tid; i < NA; i += 256) {
        const float e = expf(s_c[i] - gmax);
        s_c[i] = e;
        lsum += e;
    }
    s_red[tid] = lsum;
    __syncthreads();
#pragma unroll
    for (int st = 128; st > 0; st >>= 1) {
        if (tid < st) s_red[tid] += s_red[tid + st];
        __syncthreads();
    }
    const float inv = 1.0f / s_red[0];
    __syncthreads();
    for (int i = tid; i < NA; i += 256) s_c[i] *= inv;
    __syncthreads();

    if (tid == 0) {
        float sm = 0.0f;
#pragma unroll
        for (int j = 1; j <= 32; ++j) sm += s_c[NS + j];
        s_c[NS] += s_mm * sm;       // folded CAM value-merge
        s_c[SB]  = 0.99f;           // pinned col * 0.99 value scale
    }
    __syncthreads();

    for (int i = tid; i < NA; i += 256) scores[(size_t)bh * 512 + i] = s_c[i];
}

// ---------------- Attention phase 3: PV partials ----------------
__global__ __launch_bounds__(256) void pv_kernel(
    const float* __restrict__ qkv,     // for v_new
    const float* __restrict__ pv,      // [B,H,2048,128]
    const float* __restrict__ coeff,   // [128][512]
    const int* __restrict__ sbp, const int* __restrict__ rbp,
    float* __restrict__ partial)       // [128][8][128]
{
    constexpr int PAST = 2048, HD = 128;
    const int bh = blockIdx.y;
    const int b  = bh >> 5;
    const int h  = bh & 31;
    const int SB = sbp[0], RB = rbp[0];
    const int NS = SB + 1;
    const int NA = NS + RB + 1;
    const int CPC = (NA + 7) >> 3;
    const int i0 = blockIdx.x * CPC;
    const int i1 = min(NA, i0 + CPC);

    const int tid  = threadIdx.x;
    const int d    = tid & 127;
    const int half = tid >> 7;

    __shared__ float s_co[64];
    __shared__ float s_red[256];

    if (tid < i1 - i0) s_co[tid] = coeff[(size_t)bh * 512 + i0 + tid];
    __syncthreads();

    const float* vnew = qkv + (size_t)(8 + b) * 4096 + h * HD;

    float acc = 0.0f;
    for (int i = i0 + half; i < i1; i += 2) {
        const int s = (i < NS) ? i : (PAST - RB + (i - NS));
        const float* vr = (s < PAST)
            ? (pv + ((size_t)bh * PAST + s) * HD)
            : vnew;
        acc += s_co[i - i0] * vr[d];
    }
    s_red[tid] = acc;
    __syncthreads();
    if (tid < 128)
        partial[((size_t)bh * 8 + blockIdx.x) * HD + d] = s_red[tid] + s_red[tid + 128];
}

// ---------------- Attention phase 4: reduce partials ----------------
__global__ __launch_bounds__(256) void attn_reduce_kernel(
    const float* __restrict__ partial,  // [128][8][128]
    float* __restrict__ attn_out)       // [4][4096] == [128][128]
{
    const int idx = blockIdx.x * 256 + threadIdx.x;
    const int bh = idx >> 7;
    const int d  = idx & 127;
    float s = 0.0f;
#pragma unroll
    for (int c = 0; c < 8; ++c)
        s += partial[(size_t)bh * 1024 + c * 128 + d];
    attn_out[idx] = s;
}

extern "C" void kernel_launch(void* const* d_in, const int* in_sizes, int n_in,
                              void* d_out, int out_size, void* d_ws, size_t ws_size,
                              hipStream_t stream)
{
    const float* hs = (const float*)d_in[0];
    const float* pk = (const float*)d_in[1];
    const float* pv = (const float*)d_in[2];
    const float* am = (const float*)d_in[3];
    const float* cm = (const float*)d_in[4];
    const float* ps = (const float*)d_in[5];
    const float* Wq = (const float*)d_in[6];
    const float* bq = (const float*)d_in[7];
    const float* Wk = (const float*)d_in[8];
    const float* bk = (const float*)d_in[9];
    const float* Wv = (const float*)d_in[10];
    const float* bv = (const float*)d_in[11];
    const float* Wo = (const float*)d_in[12];
    const float* bo = (const float*)d_in[13];
    const int*   sb = (const int*)d_in[14];
    const int*   rb = (const int*)d_in[15];

    float* qkv  = (float*)d_ws;                   // 49152
    float* aout = qkv + 3 * 4 * 4096;             // 16384
    float* sc   = aout + 4 * 4096;                // 65536
    float* part = sc + 128 * 512;                 // 131072
    float* out  = (float*)d_out;

    const float scaling = 0.08838834764831845f;   // 128^-0.5

    gemv_tw_kernel<3><<<3072, 256, 0, stream>>>(hs, Wq, bq, Wk, bk, Wv, bv, scaling, qkv);

    score_kernel<<<dim3(16, 128), 256, 0, stream>>>(qkv, pk, am, cm, sb, rb, sc);
    softmax_kernel<<<128, 256, 0, stream>>>(ps, sb, rb, sc);
    pv_kernel<<<dim3(8, 128), 256, 0, stream>>>(qkv, pv, sc, sb, rb, part);
    attn_reduce_kernel<<<64, 256, 0, stream>>>(part, aout);

    gemv_tw_kernel<1><<<1024, 256, 0, stream>>>(aout, Wo, bo, Wo, bo, Wo, bo, 1.0f, out);
}